// Round 8
// baseline (121.595 us; speedup 1.0000x reference)
//
#include <hip/hip_runtime.h>
#include <hip/hip_bf16.h>

#define Bn 4
#define Sn 2048
#define Hn 768
#define NHn 12
#define Mn (Bn*Sn)
#define QKVN 2304

typedef unsigned short u16;
typedef unsigned int u32;
typedef __attribute__((ext_vector_type(8))) short short8;
typedef __attribute__((ext_vector_type(4))) float f32x4;

typedef __attribute__((address_space(1))) const u32 g_u32;
typedef __attribute__((address_space(3))) u32 l_u32;

__device__ __forceinline__ void gll16(const void* g, void* l) {
    __builtin_amdgcn_global_load_lds((g_u32*)g, (l_u32*)l, 16, 0, 0);
}

__device__ __forceinline__ u16 f2bf(float f) {
    u32 x = __float_as_uint(f);
    x += 0x7fffu + ((x >> 16) & 1u);   // round-to-nearest-even
    return (u16)(x >> 16);
}
__device__ __forceinline__ float bf2f(u16 u) {
    return __uint_as_float(((u32)u) << 16);
}

// KWAIT(N): K-tile gate. Counted vmcnt (never 0 in steady state) keeps
// prefetch loads in flight ACROSS the barrier (T4); sched_barrier(0) stops
// the compiler hoisting the following ds_reads above the gate.
#define KWAIT(N) do { \
    asm volatile("s_waitcnt vmcnt(" #N ")" ::: "memory"); \
    __builtin_amdgcn_s_barrier(); \
    __builtin_amdgcn_sched_barrier(0); \
} while (0)

// ------- fused: RoPE cos/sin table + fp32->bf16 casts (one launch) --------
__global__ __launch_bounds__(256) void prep_k(const float* __restrict__ hs,
                                              const float* __restrict__ wqkv,
                                              const float* __restrict__ wo,
                                              const int* __restrict__ pos_ids,
                                              u16* __restrict__ hs_b,
                                              u16* __restrict__ wqkv_b,
                                              u16* __restrict__ wo_b,
                                              float2* __restrict__ tab) {
    int i = blockIdx.x * 256 + threadIdx.x;
    if (i < 262144) {   // RoPE table: Mn*32 entries
        int d2 = i & 31, row = i >> 5;
        float invf = exp2f((float)d2 * -0.4152410119f);   // 10000^(-d2/32)
        float fr = (float)pos_ids[row] * invf;
        float sn, cs;
        sincosf(fr, &sn, &cs);
        tab[i] = make_float2(cs, sn);
        return;
    }
    i -= 262144;
    const float* s; u16* d; int off;
    if (i < 1572864)      { s = hs;   d = hs_b;   off = i; }
    else if (i < 2015232) { s = wqkv; d = wqkv_b; off = i - 1572864; }
    else if (i < 2162688) { s = wo;   d = wo_b;   off = i - 2015232; }
    else return;
    float4 v = ((const float4*)s)[off];
    ushort4 o;
    o.x = f2bf(v.x); o.y = f2bf(v.y); o.z = f2bf(v.z); o.w = f2bf(v.w);
    ((ushort4*)d)[off] = o;
}

// ======== 4-slot pipelined bf16 GEMM: C[M][N] = A[M][K] * B[N][K]^T ========
// 128x128 tile, BK=32, 4 waves (2x2), per-wave 64x64 (acc 4x4), 4 LDS slots
// (64 KB -> 2 blocks/CU). Per K-tile, ONE barrier:
//   KWAIT(8)       tile it resident; tiles it+1,it+2 (8 loads) stay IN FLIGHT
//   8x ds_read     frags of tile it
//   stage(it+3)    4 gll16 into slot(it-1) -- every wave's reads of it-1
//                  completed before its MFMA(it-1), which precedes gate(it):
//                  race-free WITHOUT a mid-tile drain
//   16 MFMA        under setprio(1)
// No vmcnt(0) and no lgkmcnt(0)+barrier in the main loop. LDS rows 64B =
// 4x16B granules; bank = (row&1)*16 + gran*4, so the conflict-free XOR is
// gran = g ^ ((row>>1)&3)  (exactly 8 lanes per granule-slot = wave64
// minimum; round-6's g^(row&3) was the 4-way-conflict bug). Inverse swizzle
// on the global source column (global_load_lds dest must stay linear).
// Grid is 1D with bijective XCD-chunked swizzle (nblocks % 8 == 0) so blocks
// sharing a B-panel land on the same XCD L2.
// ROPE: fused rotary via table (wave spans exactly one 64-col head block).
template <typename OUT, bool ROPE>
__global__ __launch_bounds__(256, 2) void gemm_p4(const u16* __restrict__ A,
                                                  const u16* __restrict__ Bw,
                                                  OUT* __restrict__ C,
                                                  const float2* __restrict__ tab,
                                                  int N, int K, int nbx) {
    __shared__ __align__(16) u16 As[4][128 * 32];   // 4 x 8 KB
    __shared__ __align__(16) u16 Bs[4][128 * 32];   // 4 x 8 KB (total 64 KB)
    const int t = threadIdx.x;
    const int wid = t >> 6, lane = t & 63;
    const int wr = wid >> 1, wc = wid & 1;
    const int lr = lane & 15, g = lane >> 4;

    // XCD-chunked bijective swizzle (gridDim.x % 8 == 0)
    const int nb = gridDim.x;
    const int bid = blockIdx.x;
    const int sw = (bid & 7) * (nb >> 3) + (bid >> 3);
    const long m0 = (long)(sw % nbx) * 128;
    const long n0 = (long)(sw / nbx) * 128;

    f32x4 acc[4][4] = {};

    // stage one K-tile: A 2 loads + B 2 loads per thread (4 in flight)
    auto stage = [&](int slot, int kt) {
        #pragma unroll
        for (int j = 0; j < 2; ++j) {
            int idx = t + j * 256;               // 0..511
            int row = idx >> 2, gg = idx & 3;
            int col8 = (gg ^ ((row >> 1) & 3)) * 8;   // inverse swizzle
            gll16(A + (m0 + row) * K + kt * 32 + col8, (char*)As[slot] + idx * 16);
        }
        #pragma unroll
        for (int j = 0; j < 2; ++j) {
            int idx = t + j * 256;
            int row = idx >> 2, gg = idx & 3;
            int col8 = (gg ^ ((row >> 1) & 3)) * 8;
            gll16(Bw + (n0 + row) * K + kt * 32 + col8, (char*)Bs[slot] + idx * 16);
        }
    };

    auto compute = [&](int slot, int kstage) {
        const u16* Ab = As[slot];
        const u16* Bb = Bs[slot];
        short8 af[4], bfr[4];
        #pragma unroll
        for (int nt = 0; nt < 4; ++nt) {
            int row = wc * 64 + nt * 16 + lr;
            bfr[nt] = *(const short8*)((const char*)Bb + row * 64 +
                                       ((g ^ ((row >> 1) & 3)) << 4));
        }
        #pragma unroll
        for (int mt = 0; mt < 4; ++mt) {
            int row = wr * 64 + mt * 16 + lr;
            af[mt] = *(const short8*)((const char*)Ab + row * 64 +
                                      ((g ^ ((row >> 1) & 3)) << 4));
        }
        if (kstage >= 0) stage(kstage & 3, kstage);   // re-stage slot(it-1)
        __builtin_amdgcn_s_setprio(1);
        #pragma unroll
        for (int mt = 0; mt < 4; ++mt)
            #pragma unroll
            for (int nt = 0; nt < 4; ++nt)
                acc[mt][nt] = __builtin_amdgcn_mfma_f32_16x16x32_bf16(
                    af[mt], bfr[nt], acc[mt][nt], 0, 0, 0);
        __builtin_amdgcn_s_setprio(0);
    };

    const int NT = K / 32;          // 24 for K=768
    stage(0, 0);
    stage(1, 1);
    stage(2, 2);                    // 12 loads in flight
    for (int it = 0; it + 3 < NT; ++it) {
        KWAIT(8);                   // tile it landed; it+1,it+2 still flying
        compute(it & 3, it + 3);
    }
    KWAIT(8); compute((NT - 3) & 3, -1);
    KWAIT(4); compute((NT - 2) & 3, -1);
    KWAIT(0); compute((NT - 1) & 3, -1);

    // ---- epilogue: fused RoPE via table ----
    if constexpr (ROPE) {
        if ((n0 + wc * 64) < 1536) {
            #pragma unroll
            for (int mt = 0; mt < 4; ++mt)
                #pragma unroll
                for (int r = 0; r < 4; ++r) {
                    long row = m0 + wr * 64 + mt * 16 + g * 4 + r;
                    const float2* tr = tab + row * 32;
                    #pragma unroll
                    for (int ntp = 0; ntp < 2; ++ntp) {
                        float2 cssn = tr[ntp * 16 + lr];
                        float x1 = acc[mt][ntp][r], x2 = acc[mt][ntp + 2][r];
                        acc[mt][ntp][r]     = x1 * cssn.x - x2 * cssn.y;
                        acc[mt][ntp + 2][r] = x2 * cssn.x + x1 * cssn.y;
                    }
                }
        }
    }

    #pragma unroll
    for (int mt = 0; mt < 4; ++mt)
        #pragma unroll
        for (int nt = 0; nt < 4; ++nt)
            #pragma unroll
            for (int r = 0; r < 4; ++r) {
                long row = m0 + wr * 64 + mt * 16 + g * 4 + r;
                long col = n0 + wc * 64 + nt * 16 + lr;
                float v = acc[mt][nt][r];
                if constexpr (sizeof(OUT) == 2) C[row * N + col] = (OUT)f2bf(v);
                else                            C[row * N + col] = v;
            }
}

// ---------------- windowed attention ----------------
__global__ __launch_bounds__(256) void attn_k(const u16* __restrict__ qkv,
                                              u16* __restrict__ outb) {
    const int qt = blockIdx.x, bh = blockIdx.y;
    const int b = bh / NHn, h = bh % NHn;
    const int q0 = qt * 64, kv0 = q0 - 64;
    const int t = threadIdx.x, wid = t >> 6, lane = t & 63;
    const int lr = lane & 15, g = lane >> 4;

    __shared__ __align__(16) char smem[58368];
    u16* Qs = (u16*)smem;                // [64][64] swizzled, 8192 B
    u16* Ks = (u16*)(smem + 8192);       // [192][64] swizzled, 24576 B
    u16* Vt = (u16*)(smem + 32768);      // [64][200] transposed V, 25600 B

    const size_t rowbase = (size_t)b * Sn;

    #pragma unroll
    for (int ss = 0; ss < 2; ++ss) {
        int s = t + ss * 256;
        int row = s >> 3, gg = s & 7;
        int col8 = (gg ^ (row & 7)) * 8;
        gll16(qkv + (rowbase + q0 + row) * QKVN + h * 64 + col8, (char*)Qs + s * 16);
    }
    #pragma unroll
    for (int ss = 0; ss < 6; ++ss) {
        int s = t + ss * 256;
        int row = s >> 3, gg = s & 7;
        int kk = kv0 + row;
        kk = kk < 0 ? 0 : (kk > Sn - 1 ? Sn - 1 : kk);
        int col8 = (gg ^ (row & 7)) * 8;
        gll16(qkv + (rowbase + kk) * QKVN + 768 + h * 64 + col8, (char*)Ks + s * 16);
    }
    #pragma unroll
    for (int ss = 0; ss < 6; ++ss) {
        int s = t + ss * 256;
        int krow = s >> 3, gg = s & 7;
        int kk = kv0 + krow;
        kk = kk < 0 ? 0 : (kk > Sn - 1 ? Sn - 1 : kk);
        short8 v = *(const short8*)(qkv + (rowbase + kk) * QKVN + 1536 + h * 64 + gg * 8);
        #pragma unroll
        for (int j = 0; j < 8; ++j) Vt[(gg * 8 + j) * 200 + krow] = (u16)v[j];
    }
    __syncthreads();

    f32x4 sacc[12] = {};
    #pragma unroll
    for (int kk2 = 0; kk2 < 2; ++kk2) {
        int qrow = wid * 16 + lr;
        int slot = kk2 * 4 + g;
        short8 qf = *(const short8*)((const char*)Qs + qrow * 128 + ((slot ^ (qrow & 7)) << 4));
        #pragma unroll
        for (int tl = 0; tl < 12; ++tl) {
            int krow = tl * 16 + lr;
            short8 kf = *(const short8*)((const char*)Ks + krow * 128 + ((slot ^ (krow & 7)) << 4));
            sacc[tl] = __builtin_amdgcn_mfma_f32_16x16x32_bf16(qf, kf, sacc[tl], 0, 0, 0);
        }
    }

    float p[12][4];
    float lsum[4];
    #pragma unroll
    for (int r = 0; r < 4; ++r) {
        int qq = q0 + wid * 16 + g * 4 + r;
        float mx = -3.0e38f;
        #pragma unroll
        for (int tl = 0; tl < 12; ++tl) {
            int kq = kv0 + tl * 16 + lr;
            float sc = sacc[tl][r] * 0.125f;
            int dqk = qq - kq;
            bool valid = (kq >= 0) && (kq < Sn) && (dqk <= 64) && (dqk >= -64);
            sc = valid ? sc : -3.0e38f;
            p[tl][r] = sc;
            mx = fmaxf(mx, sc);
        }
        #pragma unroll
        for (int mk = 1; mk < 16; mk <<= 1) mx = fmaxf(mx, __shfl_xor(mx, mk, 16));
        float sum = 0.f;
        #pragma unroll
        for (int tl = 0; tl < 12; ++tl) {
            float e = __expf(p[tl][r] - mx);
            p[tl][r] = e;
            sum += e;
        }
        #pragma unroll
        for (int mk = 1; mk < 16; mk <<= 1) sum += __shfl_xor(sum, mk, 16);
        lsum[r] = sum;
    }

    __syncthreads();

    u16* Pw = (u16*)(smem + wid * 6400);
    #pragma unroll
    for (int tl = 0; tl < 12; ++tl)
        #pragma unroll
        for (int r = 0; r < 4; ++r)
            Pw[(g * 4 + r) * 200 + tl * 16 + lr] = f2bf(p[tl][r]);

    f32x4 oacc[4] = {};
    #pragma unroll
    for (int ks = 0; ks < 6; ++ks) {
        short8 pf = *(const short8*)((const char*)Pw + lr * 400 + (ks * 32 + g * 8) * 2);
        #pragma unroll
        for (int dt = 0; dt < 4; ++dt) {
            short8 vf = *(const short8*)((const char*)Vt + (dt * 16 + lr) * 400 + (ks * 32 + g * 8) * 2);
            oacc[dt] = __builtin_amdgcn_mfma_f32_16x16x32_bf16(pf, vf, oacc[dt], 0, 0, 0);
        }
    }

    #pragma unroll
    for (int dt = 0; dt < 4; ++dt)
        #pragma unroll
        for (int r = 0; r < 4; ++r) {
            int row = q0 + wid * 16 + g * 4 + r;
            float v = oacc[dt][r] / lsum[r];
            outb[(rowbase + row) * Hn + h * 64 + dt * 16 + lr] = f2bf(v);
        }
}

extern "C" void kernel_launch(void* const* d_in, const int* in_sizes, int n_in,
                              void* d_out, int out_size, void* d_ws, size_t ws_size,
                              hipStream_t stream) {
    const float* hs   = (const float*)d_in[0];
    const int*   pos  = (const int*)d_in[1];
    const float* wqkv = (const float*)d_in[2];
    const float* wo   = (const float*)d_in[3];
    float* out = (float*)d_out;
    char* ws = (char*)d_ws;

    u16* hs_b   = (u16*)(ws);              // 8192*768*2   = 12,582,912
    u16* wqkv_b = (u16*)(ws + 12582912);   // 2304*768*2   =  3,538,944
    u16* wo_b   = (u16*)(ws + 16121856);   // 768*768*2    =  1,179,648
    u16* qkv    = (u16*)(ws + 17301504);   // 8192*2304*2  = 37,748,736
    u16* attn   = (u16*)(ws + 55050240);   // 8192*768*2   = 12,582,912
    float2* tab = (float2*)(ws + 55050240);   // 2MB, dead before attn_k writes

    prep_k<<<9472, 256, 0, stream>>>(hs, wqkv, wo, pos, hs_b, wqkv_b, wo_b, tab);

    // qkv = hs @ Wqkv^T with fused RoPE (4-slot BK=32 pipeline, 1152 blocks)
    gemm_p4<u16, true><<<1152, 256, 0, stream>>>(
        hs_b, wqkv_b, qkv, tab, 2304, 768, 64);

    attn_k<<<dim3(32, 48), 256, 0, stream>>>(qkv, attn);

    // out = attn @ Wo^T (fp32 out; 384 blocks -> single co-resident round)
    gemm_p4<float, false><<<384, 256, 0, stream>>>(
        attn, wo_b, out, nullptr, 768, 768, 64);
}

// Round 9
// 99.862 us; speedup vs baseline: 1.2176x; 1.2176x over previous
//
#include <hip/hip_runtime.h>
#include <hip/hip_bf16.h>

#define Bn 4
#define Sn 2048
#define Hn 768
#define NHn 12
#define Mn (Bn*Sn)
#define QKVN 2304

typedef unsigned short u16;
typedef unsigned int u32;
typedef __attribute__((ext_vector_type(8))) short short8;
typedef __attribute__((ext_vector_type(4))) float f32x4;

typedef __attribute__((address_space(1))) const u32 g_u32;
typedef __attribute__((address_space(3))) u32 l_u32;

__device__ __forceinline__ void gll16(const void* g, void* l) {
    __builtin_amdgcn_global_load_lds((g_u32*)g, (l_u32*)l, 16, 0, 0);
}

__device__ __forceinline__ u16 f2bf(float f) {
    u32 x = __float_as_uint(f);
    x += 0x7fffu + ((x >> 16) & 1u);   // round-to-nearest-even
    return (u16)(x >> 16);
}
__device__ __forceinline__ float bf2f(u16 u) {
    return __uint_as_float(((u32)u) << 16);
}

// KWAIT(N): K-tile gate. Counted vmcnt (never 0 in steady state) keeps
// prefetch loads in flight ACROSS the barrier (T4); sched_barrier(0) stops
// the compiler hoisting the following ds_reads above the gate.
#define KWAIT(N) do { \
    asm volatile("s_waitcnt vmcnt(" #N ")" ::: "memory"); \
    __builtin_amdgcn_s_barrier(); \
    __builtin_amdgcn_sched_barrier(0); \
} while (0)

// ------- fused: RoPE cos/sin table + fp32->bf16 casts (one launch) --------
__global__ __launch_bounds__(256) void prep_k(const float* __restrict__ hs,
                                              const float* __restrict__ wqkv,
                                              const float* __restrict__ wo,
                                              const int* __restrict__ pos_ids,
                                              u16* __restrict__ hs_b,
                                              u16* __restrict__ wqkv_b,
                                              u16* __restrict__ wo_b,
                                              float2* __restrict__ tab) {
    int i = blockIdx.x * 256 + threadIdx.x;
    if (i < 262144) {   // RoPE table: Mn*32 entries
        int d2 = i & 31, row = i >> 5;
        float invf = exp2f((float)d2 * -0.4152410119f);   // 10000^(-d2/32)
        float fr = (float)pos_ids[row] * invf;
        float sn, cs;
        sincosf(fr, &sn, &cs);
        tab[i] = make_float2(cs, sn);
        return;
    }
    i -= 262144;
    const float* s; u16* d; int off;
    if (i < 1572864)      { s = hs;   d = hs_b;   off = i; }
    else if (i < 2015232) { s = wqkv; d = wqkv_b; off = i - 1572864; }
    else if (i < 2162688) { s = wo;   d = wo_b;   off = i - 2015232; }
    else return;
    float4 v = ((const float4*)s)[off];
    ushort4 o;
    o.x = f2bf(v.x); o.y = f2bf(v.y); o.z = f2bf(v.z); o.w = f2bf(v.w);
    ((ushort4*)d)[off] = o;
}

// ======== 3-slot pipelined bf16 GEMM: C[M][N] = A[M][K] * B[N][K]^T ========
// 128x128 tile, BK=32, 4 waves (2x2), per-wave 64x64 (acc 4x4), 3 LDS slots
// (48 KB -> 3 blocks/CU, 12 waves/CU). Per K-tile, ONE barrier:
//   KWAIT(4)       tile it resident; tile it+1 (4 loads) stays IN FLIGHT
//   8x ds_read     frags of tile it
//   stage(it+2)    4 gll16 into slot(it-1): every wave's reads of tile it-1
//                  were consumed (lgkm-waited) by MFMA(it-1) BEFORE gate(it),
//                  so re-staging that slot after the gate is race-free
//   16 MFMA        under setprio(1)
// No vmcnt(0)/lgkmcnt(0) drains in the main loop (T4). LDS rows 64B =
// 4x16B granules; swizzle gran = g ^ ((row>>1)&3) measured conflict-free
// in round 8 (SQ_LDS_BANK_CONFLICT = 0; round-6's g^(row&3) was 4-way).
// Inverse swizzle on the global source column (gll dest stays linear).
// Plain 2D grid, x = M-tile (fastest): consecutive blocks share the B-panel
// and partition A across XCDs -- measured FETCH ~28-33 MB (round-8's XCD
// chunk swizzle gave 126 MB; reverted).
// ROPE: fused rotary via table (wave spans exactly one 64-col head block).
template <typename OUT, bool ROPE>
__global__ __launch_bounds__(256, 3) void gemm_p3(const u16* __restrict__ A,
                                                  const u16* __restrict__ Bw,
                                                  OUT* __restrict__ C,
                                                  const float2* __restrict__ tab,
                                                  int N, int K) {
    __shared__ __align__(16) u16 As[3][128 * 32];   // 3 x 8 KB
    __shared__ __align__(16) u16 Bs[3][128 * 32];   // 3 x 8 KB (total 48 KB)
    const int t = threadIdx.x;
    const int wid = t >> 6, lane = t & 63;
    const int wr = wid >> 1, wc = wid & 1;
    const long m0 = (long)blockIdx.x * 128;
    const long n0 = (long)blockIdx.y * 128;
    const int lr = lane & 15, g = lane >> 4;

    f32x4 acc[4][4] = {};

    // stage one K-tile: A 2 loads + B 2 loads per thread (4 in flight)
    auto stage = [&](int slot, int kt) {
        #pragma unroll
        for (int j = 0; j < 2; ++j) {
            int idx = t + j * 256;               // 0..511
            int row = idx >> 2, gg = idx & 3;
            int col8 = (gg ^ ((row >> 1) & 3)) * 8;   // inverse swizzle
            gll16(A + (m0 + row) * K + kt * 32 + col8, (char*)As[slot] + idx * 16);
        }
        #pragma unroll
        for (int j = 0; j < 2; ++j) {
            int idx = t + j * 256;
            int row = idx >> 2, gg = idx & 3;
            int col8 = (gg ^ ((row >> 1) & 3)) * 8;
            gll16(Bw + (n0 + row) * K + kt * 32 + col8, (char*)Bs[slot] + idx * 16);
        }
    };

    auto compute = [&](int slot, int stslot, int kstage) {
        const u16* Ab = As[slot];
        const u16* Bb = Bs[slot];
        short8 af[4], bfr[4];
        #pragma unroll
        for (int nt = 0; nt < 4; ++nt) {
            int row = wc * 64 + nt * 16 + lr;
            bfr[nt] = *(const short8*)((const char*)Bb + row * 64 +
                                       ((g ^ ((row >> 1) & 3)) << 4));
        }
        #pragma unroll
        for (int mt = 0; mt < 4; ++mt) {
            int row = wr * 64 + mt * 16 + lr;
            af[mt] = *(const short8*)((const char*)Ab + row * 64 +
                                      ((g ^ ((row >> 1) & 3)) << 4));
        }
        if (kstage >= 0) stage(stslot, kstage);   // re-stage slot(it-1)
        __builtin_amdgcn_s_setprio(1);
        #pragma unroll
        for (int mt = 0; mt < 4; ++mt)
            #pragma unroll
            for (int nt = 0; nt < 4; ++nt)
                acc[mt][nt] = __builtin_amdgcn_mfma_f32_16x16x32_bf16(
                    af[mt], bfr[nt], acc[mt][nt], 0, 0, 0);
        __builtin_amdgcn_s_setprio(0);
    };

    const int NT = K / 32;          // 24 for K=768
    stage(0, 0);
    stage(1, 1);                    // 8 loads in flight
    int sl = 0;
    for (int it = 0; it + 2 < NT; ++it) {
        KWAIT(4);                   // tile it landed; it+1 still flying
        int s2 = sl + 2; if (s2 >= 3) s2 -= 3;
        compute(sl, s2, it + 2);
        ++sl; if (sl == 3) sl = 0;
    }
    KWAIT(4); compute(sl, 0, -1);   // tile NT-2 (NT-1 still flying)
    ++sl; if (sl == 3) sl = 0;
    KWAIT(0); compute(sl, 0, -1);   // tile NT-1

    // ---- epilogue: fused RoPE via table ----
    if constexpr (ROPE) {
        if ((n0 + wc * 64) < 1536) {
            #pragma unroll
            for (int mt = 0; mt < 4; ++mt)
                #pragma unroll
                for (int r = 0; r < 4; ++r) {
                    long row = m0 + wr * 64 + mt * 16 + g * 4 + r;
                    const float2* tr = tab + row * 32;
                    #pragma unroll
                    for (int ntp = 0; ntp < 2; ++ntp) {
                        float2 cssn = tr[ntp * 16 + lr];
                        float x1 = acc[mt][ntp][r], x2 = acc[mt][ntp + 2][r];
                        acc[mt][ntp][r]     = x1 * cssn.x - x2 * cssn.y;
                        acc[mt][ntp + 2][r] = x2 * cssn.x + x1 * cssn.y;
                    }
                }
        }
    }

    #pragma unroll
    for (int mt = 0; mt < 4; ++mt)
        #pragma unroll
        for (int nt = 0; nt < 4; ++nt)
            #pragma unroll
            for (int r = 0; r < 4; ++r) {
                long row = m0 + wr * 64 + mt * 16 + g * 4 + r;
                long col = n0 + wc * 64 + nt * 16 + lr;
                float v = acc[mt][nt][r];
                if constexpr (sizeof(OUT) == 2) C[row * N + col] = (OUT)f2bf(v);
                else                            C[row * N + col] = v;
            }
}

// ---------------- windowed attention ----------------
__global__ __launch_bounds__(256) void attn_k(const u16* __restrict__ qkv,
                                              u16* __restrict__ outb) {
    const int qt = blockIdx.x, bh = blockIdx.y;
    const int b = bh / NHn, h = bh % NHn;
    const int q0 = qt * 64, kv0 = q0 - 64;
    const int t = threadIdx.x, wid = t >> 6, lane = t & 63;
    const int lr = lane & 15, g = lane >> 4;

    __shared__ __align__(16) char smem[58368];
    u16* Qs = (u16*)smem;                // [64][64] swizzled, 8192 B
    u16* Ks = (u16*)(smem + 8192);       // [192][64] swizzled, 24576 B
    u16* Vt = (u16*)(smem + 32768);      // [64][200] transposed V, 25600 B

    const size_t rowbase = (size_t)b * Sn;

    #pragma unroll
    for (int ss = 0; ss < 2; ++ss) {
        int s = t + ss * 256;
        int row = s >> 3, gg = s & 7;
        int col8 = (gg ^ (row & 7)) * 8;
        gll16(qkv + (rowbase + q0 + row) * QKVN + h * 64 + col8, (char*)Qs + s * 16);
    }
    #pragma unroll
    for (int ss = 0; ss < 6; ++ss) {
        int s = t + ss * 256;
        int row = s >> 3, gg = s & 7;
        int kk = kv0 + row;
        kk = kk < 0 ? 0 : (kk > Sn - 1 ? Sn - 1 : kk);
        int col8 = (gg ^ (row & 7)) * 8;
        gll16(qkv + (rowbase + kk) * QKVN + 768 + h * 64 + col8, (char*)Ks + s * 16);
    }
    #pragma unroll
    for (int ss = 0; ss < 6; ++ss) {
        int s = t + ss * 256;
        int krow = s >> 3, gg = s & 7;
        int kk = kv0 + krow;
        kk = kk < 0 ? 0 : (kk > Sn - 1 ? Sn - 1 : kk);
        short8 v = *(const short8*)(qkv + (rowbase + kk) * QKVN + 1536 + h * 64 + gg * 8);
        #pragma unroll
        for (int j = 0; j < 8; ++j) Vt[(gg * 8 + j) * 200 + krow] = (u16)v[j];
    }
    __syncthreads();

    f32x4 sacc[12] = {};
    #pragma unroll
    for (int kk2 = 0; kk2 < 2; ++kk2) {
        int qrow = wid * 16 + lr;
        int slot = kk2 * 4 + g;
        short8 qf = *(const short8*)((const char*)Qs + qrow * 128 + ((slot ^ (qrow & 7)) << 4));
        #pragma unroll
        for (int tl = 0; tl < 12; ++tl) {
            int krow = tl * 16 + lr;
            short8 kf = *(const short8*)((const char*)Ks + krow * 128 + ((slot ^ (krow & 7)) << 4));
            sacc[tl] = __builtin_amdgcn_mfma_f32_16x16x32_bf16(qf, kf, sacc[tl], 0, 0, 0);
        }
    }

    float p[12][4];
    float lsum[4];
    #pragma unroll
    for (int r = 0; r < 4; ++r) {
        int qq = q0 + wid * 16 + g * 4 + r;
        float mx = -3.0e38f;
        #pragma unroll
        for (int tl = 0; tl < 12; ++tl) {
            int kq = kv0 + tl * 16 + lr;
            float sc = sacc[tl][r] * 0.125f;
            int dqk = qq - kq;
            bool valid = (kq >= 0) && (kq < Sn) && (dqk <= 64) && (dqk >= -64);
            sc = valid ? sc : -3.0e38f;
            p[tl][r] = sc;
            mx = fmaxf(mx, sc);
        }
        #pragma unroll
        for (int mk = 1; mk < 16; mk <<= 1) mx = fmaxf(mx, __shfl_xor(mx, mk, 16));
        float sum = 0.f;
        #pragma unroll
        for (int tl = 0; tl < 12; ++tl) {
            float e = __expf(p[tl][r] - mx);
            p[tl][r] = e;
            sum += e;
        }
        #pragma unroll
        for (int mk = 1; mk < 16; mk <<= 1) sum += __shfl_xor(sum, mk, 16);
        lsum[r] = sum;
    }

    __syncthreads();

    u16* Pw = (u16*)(smem + wid * 6400);
    #pragma unroll
    for (int tl = 0; tl < 12; ++tl)
        #pragma unroll
        for (int r = 0; r < 4; ++r)
            Pw[(g * 4 + r) * 200 + tl * 16 + lr] = f2bf(p[tl][r]);

    f32x4 oacc[4] = {};
    #pragma unroll
    for (int ks = 0; ks < 6; ++ks) {
        short8 pf = *(const short8*)((const char*)Pw + lr * 400 + (ks * 32 + g * 8) * 2);
        #pragma unroll
        for (int dt = 0; dt < 4; ++dt) {
            short8 vf = *(const short8*)((const char*)Vt + (dt * 16 + lr) * 400 + (ks * 32 + g * 8) * 2);
            oacc[dt] = __builtin_amdgcn_mfma_f32_16x16x32_bf16(pf, vf, oacc[dt], 0, 0, 0);
        }
    }

    #pragma unroll
    for (int dt = 0; dt < 4; ++dt)
        #pragma unroll
        for (int r = 0; r < 4; ++r) {
            int row = q0 + wid * 16 + g * 4 + r;
            float v = oacc[dt][r] / lsum[r];
            outb[(rowbase + row) * Hn + h * 64 + dt * 16 + lr] = f2bf(v);
        }
}

extern "C" void kernel_launch(void* const* d_in, const int* in_sizes, int n_in,
                              void* d_out, int out_size, void* d_ws, size_t ws_size,
                              hipStream_t stream) {
    const float* hs   = (const float*)d_in[0];
    const int*   pos  = (const int*)d_in[1];
    const float* wqkv = (const float*)d_in[2];
    const float* wo   = (const float*)d_in[3];
    float* out = (float*)d_out;
    char* ws = (char*)d_ws;

    u16* hs_b   = (u16*)(ws);              // 8192*768*2   = 12,582,912
    u16* wqkv_b = (u16*)(ws + 12582912);   // 2304*768*2   =  3,538,944
    u16* wo_b   = (u16*)(ws + 16121856);   // 768*768*2    =  1,179,648
    u16* qkv    = (u16*)(ws + 17301504);   // 8192*2304*2  = 37,748,736
    u16* attn   = (u16*)(ws + 55050240);   // 8192*768*2   = 12,582,912
    float2* tab = (float2*)(ws + 55050240);   // 2MB, dead before attn_k writes

    prep_k<<<9472, 256, 0, stream>>>(hs, wqkv, wo, pos, hs_b, wqkv_b, wo_b, tab);

    // qkv = hs @ Wqkv^T with fused RoPE (3-slot BK=32 pipeline, 3 blocks/CU)
    gemm_p3<u16, true><<<dim3(64, 18), 256, 0, stream>>>(
        hs_b, wqkv_b, qkv, tab, 2304, 768);

    attn_k<<<dim3(32, 48), 256, 0, stream>>>(qkv, attn);

    // out = attn @ Wo^T (fp32 out)
    gemm_p3<float, false><<<dim3(64, 6), 256, 0, stream>>>(
        attn, wo_b, out, nullptr, 768, 768);
}